// Round 7
// baseline (273.537 us; speedup 1.0000x reference)
//
#include <hip/hip_runtime.h>
#include <hip/hip_bf16.h>
#include <math.h>

typedef __bf16 bf16x8 __attribute__((ext_vector_type(8)));
typedef unsigned short u16x8 __attribute__((ext_vector_type(8)));
typedef float f32x4 __attribute__((ext_vector_type(4)));

#define CDIM 1024
#define DDIM 64
#define NB   16384
#define NROWS 65536

// float -> bf16 bits, round-to-nearest-even (finite inputs)
__device__ __forceinline__ unsigned short f2bf(float x){
  unsigned int u = __float_as_uint(x);
  unsigned int lsb = (u >> 16) & 1u;
  u += 0x7fffu + lsb;
  return (unsigned short)(u >> 16);
}

__device__ __forceinline__ void load_lds16(const float* g, float* l){
  __builtin_amdgcn_global_load_lds(
      (const __attribute__((address_space(1))) void*)g,
      (__attribute__((address_space(3))) void*)l, 16, 0, 0);
}

// ---------------- K0: Wd -> fragment-major bf16 Wf; seln = l2norm(sel); gbu --------
__global__ __launch_bounds__(256) void dsa_prep(
    const float* __restrict__ Wd, const float* __restrict__ tf,
    const float* __restrict__ bu, const float* __restrict__ gam,
    unsigned short* __restrict__ Wf, float* __restrict__ seln,
    float* __restrict__ gbu){
  int bb = blockIdx.x, tid = threadIdx.x;
  if (bb < 32){
    int g = bb*256 + tid;            // 0..8191
    int lane = g & 63, tj = g >> 6;  // tj = t*4+j
    int n  = ((tj & 3) << 4) + (lane & 15);
    int k0 = ((tj >> 2) << 5) + ((lane >> 4) << 3);
    u16x8 uv;
    #pragma unroll
    for (int e=0;e<8;e++) uv[e] = f2bf(Wd[(k0+e)*DDIM + n]);
    *(u16x8*)(Wf + (size_t)g*8) = uv;
  } else {
    int w = tid >> 6, lane = tid & 63;   // wave w = batch w
    float x = tf[w*(20*512) + lane];     // text_features[b,0,lane]
    float sq = x*x;
    #pragma unroll
    for (int m=1; m<64; m<<=1) sq += __shfl_xor(sq, m);
    seln[w*64 + lane] = x / fmaxf(sqrtf(sq), 1e-12f);
    float g = gam[0];
    f32x4 b4 = *(const f32x4*)(bu + tid*4);
    *(f32x4*)(gbu + tid*4) = g*b4;
  }
}

// ---------------- K1a: READ-ONLY fused  a=gelu(X@Wd+bd) | scores --------------------
// X via global_load_lds into per-wave-private 2-slot ring. NO stores in the loop,
// so vmcnt counts are exact: vmcnt(8)=DMA(P) landed, vmcnt(4)=B(P) landed.
__global__ __launch_bounds__(256, 4) void dsa_gemm(
    const float* __restrict__ X, const unsigned short* __restrict__ Wf,
    const float* __restrict__ bd, const float* __restrict__ seln,
    float* __restrict__ a_out, float* __restrict__ scores)
{
  __shared__ __align__(16) float AsF[8192];   // 4 waves x 2 slots x 1024 floats
  const int tid  = threadIdx.x;
  const int lane = tid & 63, w = tid >> 6;
  const int lr = lane & 15, lq = lane >> 4;
  const int row0 = blockIdx.x*64 + w*16;      // this wave's 16 rows
  const int batch = blockIdx.x >> 8;

  const int rsub = lane >> 4;                 // row-within-DMA-issue
  const int ch   = lane & 15;                 // 16B chunk slot in LDS row
  const float* gbase = X + (size_t)(row0 + rsub)*CDIM;
  float* asw = AsF + w*2048;                  // this wave's 2 slots
  const bf16x8* wf8 = (const bf16x8*)Wf;

  bf16x8 B[8];
  f32x4 acc[4] = {};

  // DMA one 16x64 phase-tile of X into slot SL (pre-swizzled source: chunk^row&7)
#define DMA(P, SL) { \
    { int gc = ch ^ ((0*4 + rsub)&7); \
      load_lds16(gbase + (size_t)(0*4)*CDIM + (P)*64 + gc*4, asw + (SL)*1024 + 0*256); } \
    { int gc = ch ^ ((1*4 + rsub)&7); \
      load_lds16(gbase + (size_t)(1*4)*CDIM + (P)*64 + gc*4, asw + (SL)*1024 + 1*256); } \
    { int gc = ch ^ ((2*4 + rsub)&7); \
      load_lds16(gbase + (size_t)(2*4)*CDIM + (P)*64 + gc*4, asw + (SL)*1024 + 2*256); } \
    { int gc = ch ^ ((3*4 + rsub)&7); \
      load_lds16(gbase + (size_t)(3*4)*CDIM + (P)*64 + gc*4, asw + (SL)*1024 + 3*256); } \
    asm volatile("" ::: "memory"); }

#define LDB(P) { \
    B[0] = wf8[(((P)*2+0)*4+0)*64 + lane]; \
    B[1] = wf8[(((P)*2+0)*4+1)*64 + lane]; \
    B[2] = wf8[(((P)*2+0)*4+2)*64 + lane]; \
    B[3] = wf8[(((P)*2+0)*4+3)*64 + lane]; \
    B[4] = wf8[(((P)*2+1)*4+0)*64 + lane]; \
    B[5] = wf8[(((P)*2+1)*4+1)*64 + lane]; \
    B[6] = wf8[(((P)*2+1)*4+2)*64 + lane]; \
    B[7] = wf8[(((P)*2+1)*4+3)*64 + lane]; }

#define STEP(S, SL) { \
    int c0 = (((S)*8 + lq*2 + 0) ^ (lr & 7)); \
    int c1 = (((S)*8 + lq*2 + 1) ^ (lr & 7)); \
    f32x4 xa = *(const f32x4*)(asw + (SL)*1024 + lr*64 + c0*4); \
    f32x4 xb = *(const f32x4*)(asw + (SL)*1024 + lr*64 + c1*4); \
    bf16x8 av; \
    av[0]=(__bf16)xa[0]; av[1]=(__bf16)xa[1]; av[2]=(__bf16)xa[2]; av[3]=(__bf16)xa[3]; \
    av[4]=(__bf16)xb[0]; av[5]=(__bf16)xb[1]; av[6]=(__bf16)xb[2]; av[7]=(__bf16)xb[3]; \
    acc[0] = __builtin_amdgcn_mfma_f32_16x16x32_bf16(av, B[4*(S)+0], acc[0], 0,0,0); \
    acc[1] = __builtin_amdgcn_mfma_f32_16x16x32_bf16(av, B[4*(S)+1], acc[1], 0,0,0); \
    acc[2] = __builtin_amdgcn_mfma_f32_16x16x32_bf16(av, B[4*(S)+2], acc[2], 0,0,0); \
    acc[3] = __builtin_amdgcn_mfma_f32_16x16x32_bf16(av, B[4*(S)+3], acc[3], 0,0,0); }

  // steady phase P: wait DMA(P) -> issue DMA(P+1) -> read X(P) -> wait B(P)
  // -> MFMA -> issue LDB(P+1).  (store-free => counts exact)
#define PH(P, W1) { \
    asm volatile("s_waitcnt vmcnt(" W1 ")" ::: "memory"); \
    DMA((P)+1, ((P)+1)&1) \
    asm volatile("s_waitcnt vmcnt(4)" ::: "memory"); \
    STEP(0, (P)&1) STEP(1, (P)&1) \
    LDB((P)+1) \
    asm volatile("" ::: "memory"); }

  DMA(0, 0)
  LDB(0)
  DMA(1, 1)
  // phase 0: wait DMA(0): younger = LDB(0) 8 + DMA(1) 4 = 12
  PH(0,"12")
  PH(1,"8")  PH(2,"8")  PH(3,"8")  PH(4,"8")  PH(5,"8")
  PH(6,"8")  PH(7,"8")  PH(8,"8")  PH(9,"8")  PH(10,"8")
  PH(11,"8") PH(12,"8") PH(13,"8") PH(14,"8")
  // phase 15: wait DMA(15): younger = LDB(15) 8; then B(15): vmcnt(0)
  asm volatile("s_waitcnt vmcnt(8)" ::: "memory");
  asm volatile("s_waitcnt vmcnt(0)" ::: "memory");
  STEP(0, 1) STEP(1, 1)

#undef DMA
#undef LDB
#undef STEP
#undef PH

  // Epilogue: +bd, exact gelu, write a, fused l2norm-dot scores
  const float* selb = seln + batch*64;
  float ss[4] = {0,0,0,0}, dt[4] = {0,0,0,0};
  float gv[4][4];
  #pragma unroll
  for (int j=0;j<4;j++){
    int col = 16*j + lr;
    float bdc = bd[col];
    float sc  = selb[col];
    #pragma unroll
    for (int r=0;r<4;r++){
      float y = acc[j][r] + bdc;
      float g = 0.5f * y * (1.0f + erff(y * 0.70710678118654752f));
      gv[j][r] = g;
      ss[r] += g*g;
      dt[r] += g*sc;
    }
  }
  #pragma unroll
  for (int r=0;r<4;r++){
    int row = row0 + 4*lq + r;
    #pragma unroll
    for (int j=0;j<4;j++)
      a_out[(size_t)row*DDIM + 16*j + lr] = gv[j][r];
  }
  #pragma unroll
  for (int m=1;m<16;m<<=1){
    #pragma unroll
    for (int r=0;r<4;r++){
      ss[r] += __shfl_xor(ss[r], m);
      dt[r] += __shfl_xor(dt[r], m);
    }
  }
  if (lr == 0){
    #pragma unroll
    for (int r=0;r<4;r++)
      scores[row0 + 4*lq + r] = dt[r] / fmaxf(sqrtf(ss[r]), 1e-12f);
  }
}

// ---------------- K1b: pure streaming copy  out = X + gamma*bu ----------------------
// m13 pattern: grid-stride f32x4, tiny VGPR, 2048 blocks -> 32 waves/CU.
// gamma*bu is lane-invariant across the grid stride (stride % row == 0).
__global__ __launch_bounds__(256) void dsa_copy(
    const float* __restrict__ X, const float* __restrict__ gbu,
    float* __restrict__ out)
{
  const f32x4* x4 = (const f32x4*)X;
  f32x4*       o4 = (f32x4*)out;
  const f32x4  gb = ((const f32x4*)gbu)[threadIdx.x];  // (i & 255) == tid, invariant
  size_t i = (size_t)blockIdx.x*256 + threadIdx.x;
  const size_t S = (size_t)2048*256;
  #pragma unroll 8
  for (int k = 0; k < 32; ++k, i += S)
    o4[i] = x4[i] + gb;
}

// ---------------- K2: per-batch exact top-64 via 8-bit radix select -----------------
__global__ __launch_bounds__(1024) void dsa_topk(const float* __restrict__ scores,
                                                 int* __restrict__ idxo){
  const int b = blockIdx.x, tid = threadIdx.x;
  const float* s = scores + b*NB;
  const int base = tid*16;
  unsigned key[16];
  #pragma unroll
  for (int i=0;i<16;i+=4){
    f32x4 f = *(const f32x4*)(s + base + i);
    #pragma unroll
    for (int c=0;c<4;c++){
      unsigned u = __float_as_uint(f[c]);
      key[i+c] = (u & 0x80000000u) ? ~u : (u | 0x80000000u);  // ascending uint order
    }
  }

  __shared__ unsigned bins[256];
  __shared__ unsigned sh_pref, sh_R;
  __shared__ int selIdx[64];
  __shared__ int eqIdx[256];
  __shared__ unsigned selCnt, eqCnt;

  unsigned prefix = 0, R = 64;
  for (int pass=0; pass<4; ++pass){
    const int shift = 24 - pass*8;
    if (tid < 256) bins[tid] = 0;
    __syncthreads();
    #pragma unroll
    for (int i=0;i<16;i++){
      unsigned k = key[i];
      bool ok;
      if (pass == 0) ok = true;
      else           ok = ((k >> (shift+8)) == prefix);
      if (ok) atomicAdd(&bins[(k >> shift) & 255u], 1u);
    }
    __syncthreads();
    if (tid < 64){
      unsigned c0 = bins[tid*4+0], c1 = bins[tid*4+1];
      unsigned c2 = bins[tid*4+2], c3 = bins[tid*4+3];
      unsigned gs = c0+c1+c2+c3;
      unsigned suf = gs;                       // inclusive suffix sum over 64 groups
      #pragma unroll
      for (int m=1;m<64;m<<=1){
        unsigned o = __shfl_down(suf, m);
        if (tid + m < 64) suf += o;
      }
      unsigned above = suf - gs;               // strictly-above-this-group count
      if (above < R && R <= suf){              // exactly one lane
        unsigned a3 = above;
        unsigned a2 = a3 + c3;
        unsigned a1 = a2 + c2;
        unsigned a0 = a1 + c1;
        unsigned bb, ab;
        if      (R <= a3 + c3){ bb = 3; ab = a3; }
        else if (R <= a2 + c2){ bb = 2; ab = a2; }
        else if (R <= a1 + c1){ bb = 1; ab = a1; }
        else                  { bb = 0; ab = a0; }
        sh_pref = (prefix << 8) | (tid*4 + bb);
        sh_R = R - ab;
      }
    }
    __syncthreads();
    prefix = sh_pref; R = sh_R;
    __syncthreads();
  }
  // prefix == exact key of 64th-largest; need R of the equal keys (smallest indices)
  if (tid == 0){ selCnt = 0; eqCnt = 0; }
  __syncthreads();
  #pragma unroll
  for (int i=0;i<16;i++){
    unsigned k = key[i];
    if (k > prefix){
      selIdx[atomicAdd(&selCnt, 1u)] = base + i;
    } else if (k == prefix){
      unsigned p = atomicAdd(&eqCnt, 1u);
      if (p < 256) eqIdx[p] = base + i;
    }
  }
  __syncthreads();
  if (tid == 0){
    unsigned n = eqCnt < 256u ? eqCnt : 256u;
    unsigned have = selCnt;
    for (unsigned r2 = 0; r2 < R; ++r2){
      int best = 0x7fffffff, bi = -1;
      for (unsigned e=0; e<n; e++)
        if (eqIdx[e] < best){ best = eqIdx[e]; bi = (int)e; }
      selIdx[have + r2] = best;
      eqIdx[bi] = 0x7fffffff;
    }
  }
  __syncthreads();
  if (tid < 64){                    // wave-0 bitonic sort ascending
    int x = selIdx[tid];
    #pragma unroll
    for (int size=2; size<=64; size<<=1){
      #pragma unroll
      for (int stride=size>>1; stride>0; stride>>=1){
        int ox = __shfl_xor(x, stride);
        bool up = ((tid & size) == 0);
        bool takeMin = (((tid & stride) == 0) == up);
        int mn = x < ox ? x : ox, mx = x < ox ? ox : x;
        x = takeMin ? mn : mx;
      }
    }
    idxo[b*64 + tid] = x;
  }
}

// ---------------- K3: fused per-batch tail: gather+LN+QKV+attention+Wo+enh ----------
__global__ __launch_bounds__(512) void dsa_tail(
    const float* __restrict__ a, const float* __restrict__ mq, const int* __restrict__ idx,
    const float* __restrict__ lnw, const float* __restrict__ lnb,
    const float* __restrict__ Wq, const float* __restrict__ bq,
    const float* __restrict__ Wk, const float* __restrict__ bk,
    const float* __restrict__ Wv, const float* __restrict__ bv,
    const float* __restrict__ Wo, const float* __restrict__ bo,
    float* __restrict__ enh)
{
  __shared__ float xln[80][64];
  __shared__ float qS[80][64];
  __shared__ float vS[80][68];     // padded: PV 4-group read -> 2-way (free)
  __shared__ float kT[64][81];     // K transposed, padded
  __shared__ float oS[80][64];
  __shared__ float WoS[64][64];
  __shared__ float rowbuf[8][84];  // per-wave prob row
  __shared__ int   sidx[64];

  const int b = blockIdx.x, tid = threadIdx.x;
  const int w = tid >> 6, lane = tid & 63;

  if (tid < 64) sidx[tid] = idx[b*64 + tid];
  for (int e = tid; e < 4096; e += 512) WoS[e>>6][e&63] = Wo[e];  // overlap with P0
  __syncthreads();

  // ---- P0: gather comb rows + layernorm (10 rows per wave, loads prefetched) ----
  {
    float lw = lnw[lane], lb = lnb[lane];
    float vals[10];
    #pragma unroll
    for (int i=0;i<10;i++){
      int s = w + 8*i;
      vals[i] = (s < 16) ? mq[s*64 + lane]
                         : a[((size_t)b*NB + sidx[s-16])*64 + lane];
    }
    #pragma unroll
    for (int i=0;i<10;i++){
      int s = w + 8*i;
      float val = vals[i];
      float sm = val, sq = val*val;
      #pragma unroll
      for (int m=1;m<64;m<<=1){ sm += __shfl_xor(sm,m); sq += __shfl_xor(sq,m); }
      float mu  = sm * (1.0f/64.0f);
      float var = sq * (1.0f/64.0f) - mu*mu;
      xln[s][lane] = (val - mu) * rsqrtf(var + 1e-5f) * lw + lb;
    }
  }
  __syncthreads();

  // ---- P1: QKV projections. W column in registers per lane. ----
  #pragma unroll 1
  for (int m = 0; m < 3; ++m){
    const float* Wm = (m==0) ? Wq : (m==1) ? Wk : Wv;
    const float* bm = (m==0) ? bq : (m==1) ? bk : bv;
    float wreg[64];
    #pragma unroll
    for (int c=0;c<64;c++) wreg[c] = Wm[c*64 + lane];
    float bias = bm[lane];
    #pragma unroll 1
    for (int s = w; s < 80; s += 8){
      float accv = bias;
      #pragma unroll
      for (int c4=0;c4<16;c4++){
        f32x4 x4 = *(const f32x4*)&xln[s][c4*4];
        accv += x4[0]*wreg[c4*4+0] + x4[1]*wreg[c4*4+1]
              + x4[2]*wreg[c4*4+2] + x4[3]*wreg[c4*4+3];
      }
      if (m==0)      qS[s][lane]  = accv;
      else if (m==1) kT[lane][s]  = accv;
      else           vS[s][lane]  = accv;
    }
  }
  __syncthreads();

  // ---- P2: fused scores+softmax+PV. Wave pair per head; rows 16..79 only. ----
  {
    const int h = w >> 1, h16 = h*16;
    const int i0 = 16 + (w & 1)*32;
    const int jj = lane >> 4, dd = lane & 15;
    #pragma unroll 2
    for (int ii = 0; ii < 32; ++ii){
      int i = i0 + ii;
      float v0 = 0.f, v1 = 0.f;
      #pragma unroll
      for (int d=0; d<16; ++d){
        float qd = qS[i][h16+d];
        v0 = fmaf(qd, kT[h16+d][lane],    v0);
        v1 = fmaf(qd, kT[h16+d][64 + dd], v1);
      }
      v0 *= 0.25f; v1 *= 0.25f;
      float mx = fmaxf(v0, v1);
      #pragma unroll
      for (int m2=1;m2<64;m2<<=1) mx = fmaxf(mx, __shfl_xor(mx,m2));
      float e0 = expf(v0 - mx);
      float e1 = expf(v1 - mx);
      float sm = e0 + ((lane < 16) ? e1 : 0.f);
      #pragma unroll
      for (int m2=1;m2<64;m2<<=1) sm += __shfl_xor(sm,m2);
      float inv = 1.0f / sm;
      rowbuf[w][lane] = e0 * inv;
      if (lane < 16) rowbuf[w][64+dd] = e1 * inv;
      // PV partials: lane = (jj,dd); same-wave LDS ordering guarantees visibility
      float part = 0.f;
      #pragma unroll
      for (int tt=0; tt<20; ++tt){
        int j = jj*20 + tt;
        part = fmaf(rowbuf[w][j], vS[j][h16+dd], part);
      }
      part += __shfl_xor(part, 16);
      part += __shfl_xor(part, 32);
      if (lane < 16) oS[i][h16+dd] = part;
    }
  }
  __syncthreads();

  // ---- P3: enh = comb_sparse + o @ Wo + bo ----
  for (int e = tid; e < 4096; e += 512){
    int s16 = e >> 6, cc = e & 63;
    float accv = bo[cc];
    #pragma unroll
    for (int d4=0; d4<16; ++d4){
      f32x4 o4 = *(const f32x4*)&oS[16+s16][d4*4];
      accv += o4[0]*WoS[d4*4+0][cc] + o4[1]*WoS[d4*4+1][cc]
            + o4[2]*WoS[d4*4+2][cc] + o4[3]*WoS[d4*4+3][cc];
    }
    float cmb = a[((size_t)b*NB + sidx[s16])*64 + cc];
    enh[(b*64 + s16)*64 + cc] = cmb + accv;
  }
}

// ---------------- K4: out[b, idx[j], :] += gamma * (enh[j] @ Wu) --------------------
__global__ __launch_bounds__(256) void dsa_scatter(
    const float* __restrict__ enh, const float* __restrict__ Wu,
    const float* __restrict__ gam, const int* __restrict__ idx,
    float* __restrict__ out)
{
  int blk = blockIdx.x;
  int b = blk >> 6, j = blk & 63;
  int tid = threadIdx.x;
  __shared__ float er[64];
  if (tid < 64) er[tid] = enh[(b*64+j)*64 + tid];
  __syncthreads();
  int n = idx[b*64 + j];
  float gamma = gam[0];
  int c0 = tid*4;
  float ax=0.f, ay=0.f, az=0.f, aw=0.f;
  #pragma unroll 8
  for (int d=0; d<64; ++d){
    float ev = er[d];
    f32x4 wr = *(const f32x4*)(Wu + d*CDIM + c0);
    ax += ev*wr[0]; ay += ev*wr[1]; az += ev*wr[2]; aw += ev*wr[3];
  }
  float* op = out + ((size_t)b*NB + n)*CDIM + c0;
  f32x4 cu = *(f32x4*)op;
  cu[0] += gamma*ax; cu[1] += gamma*ay; cu[2] += gamma*az; cu[3] += gamma*aw;
  *(f32x4*)op = cu;
}

extern "C" void kernel_launch(void* const* d_in, const int* in_sizes, int n_in,
                              void* d_out, int out_size, void* d_ws, size_t ws_size,
                              hipStream_t stream) {
  const float* X    = (const float*)d_in[0];
  const float* tf   = (const float*)d_in[1];
  const float* Wd   = (const float*)d_in[2];
  const float* bd   = (const float*)d_in[3];
  const float* Wu   = (const float*)d_in[4];
  const float* bu   = (const float*)d_in[5];
  const float* mq   = (const float*)d_in[6];
  const float* Wq   = (const float*)d_in[7];
  const float* bq   = (const float*)d_in[8];
  const float* Wk   = (const float*)d_in[9];
  const float* bk   = (const float*)d_in[10];
  const float* Wv   = (const float*)d_in[11];
  const float* bv   = (const float*)d_in[12];
  const float* Wo   = (const float*)d_in[13];
  const float* bo   = (const float*)d_in[14];
  const float* lnw  = (const float*)d_in[15];
  const float* lnb  = (const float*)d_in[16];
  const float* gam  = (const float*)d_in[17];
  float* out = (float*)d_out;

  float* ws_a               = (float*)d_ws;                 // 65536*64
  unsigned short* ws_wf     = (unsigned short*)(ws_a + (size_t)NROWS*DDIM);
  float* ws_scores          = (float*)(ws_wf + 64*CDIM);    // 65536
  float* ws_seln            = ws_scores + NROWS;            // 256
  float* ws_gbu             = ws_seln + 256;                // 1024
  int*   ws_idx             = (int*)(ws_gbu + 1024);        // 256
  float* ws_enh             = (float*)(ws_idx + 256);       // 4*64*64

  dsa_prep   <<<33,   256, 0, stream>>>(Wd, tf, bu, gam, ws_wf, ws_seln, ws_gbu);
  dsa_gemm   <<<1024, 256, 0, stream>>>(X, ws_wf, bd, ws_seln, ws_a, ws_scores);
  dsa_topk   <<<4,   1024, 0, stream>>>(ws_scores, ws_idx);
  dsa_tail   <<<4,    512, 0, stream>>>(ws_a, mq, ws_idx, lnw, lnb,
                                        Wq, bq, Wk, bk, Wv, bv, Wo, bo, ws_enh);
  dsa_copy   <<<2048, 256, 0, stream>>>(X, ws_gbu, out);
  dsa_scatter<<<256,  256, 0, stream>>>(ws_enh, Wu, gam, ws_idx, out);
}

// Round 8
// 240.810 us; speedup vs baseline: 1.1359x; 1.1359x over previous
//
#include <hip/hip_runtime.h>
#include <hip/hip_bf16.h>
#include <math.h>

typedef __bf16 bf16x8 __attribute__((ext_vector_type(8)));
typedef unsigned short u16x8 __attribute__((ext_vector_type(8)));
typedef float f32x4 __attribute__((ext_vector_type(4)));

#define CDIM 1024
#define DDIM 64
#define NB   16384
#define NROWS 65536

// float -> bf16 bits, round-to-nearest-even (finite inputs)
__device__ __forceinline__ unsigned short f2bf(float x){
  unsigned int u = __float_as_uint(x);
  unsigned int lsb = (u >> 16) & 1u;
  u += 0x7fffu + lsb;
  return (unsigned short)(u >> 16);
}

// ---------------- K0: Wd -> fragment-major bf16 Wf; seln = l2norm(sel); gbu --------
// Wf element index: (t*4 + j)*64*8 + lane*8 + e  holds  Wd[k][n],
//   n = j*16 + (lane&15),  k = t*32 + (lane>>4)*8 + e      (t = 0..31, j = 0..3)
__global__ __launch_bounds__(256) void dsa_prep(
    const float* __restrict__ Wd, const float* __restrict__ tf,
    const float* __restrict__ bu, const float* __restrict__ gam,
    unsigned short* __restrict__ Wf, float* __restrict__ seln,
    float* __restrict__ gbu){
  int bb = blockIdx.x, tid = threadIdx.x;
  if (bb < 32){
    int g = bb*256 + tid;            // 0..8191
    int lane = g & 63, tj = g >> 6;  // tj = t*4+j
    int n  = ((tj & 3) << 4) + (lane & 15);
    int k0 = ((tj >> 2) << 5) + ((lane >> 4) << 3);
    u16x8 uv;
    #pragma unroll
    for (int e=0;e<8;e++) uv[e] = f2bf(Wd[(k0+e)*DDIM + n]);
    *(u16x8*)(Wf + (size_t)g*8) = uv;
  } else {
    int w = tid >> 6, lane = tid & 63;   // wave w = batch w
    float x = tf[w*(20*512) + lane];     // text_features[b,0,lane]
    float sq = x*x;
    #pragma unroll
    for (int m=1; m<64; m<<=1) sq += __shfl_xor(sq, m);
    seln[w*64 + lane] = x / fmaxf(sqrtf(sq), 1e-12f);
    float g = gam[0];
    f32x4 b4 = *(const f32x4*)(bu + tid*4);
    *(f32x4*)(gbu + tid*4) = g*b4;
  }
}

// ---------------- K1: fused  out=X+gbu | a=gelu(X@Wd+bd) | scores -------------------
// Deep register pipeline: X and B per-lane loads issued 2 phases ahead in rotating
// [t%3] buffers (statically indexed after full unroll). No LDS for X/B, no barriers,
// no inline asm - compiler inserts exact counted vmcnt. gbu via LDS (lgkm stream).
__global__ __launch_bounds__(256) void dsa_main(
    const float* __restrict__ X, const unsigned short* __restrict__ Wf,
    const float* __restrict__ bd, const float* __restrict__ gbu,
    const float* __restrict__ seln,
    float* __restrict__ out, float* __restrict__ a_out, float* __restrict__ scores)
{
  __shared__ __align__(16) float gbS[1024];   // gamma*bu
  const int tid  = threadIdx.x;
  const int lane = tid & 63, w = tid >> 6;
  const int lr = lane & 15, lq = lane >> 4;
  const int row0 = blockIdx.x*64 + w*16;      // this wave's 16 rows
  const int batch = blockIdx.x >> 8;          // 256 blocks per batch

  { f32x4 t = *(const f32x4*)(gbu + tid*4); *(f32x4*)(gbS + tid*4) = t; }
  __syncthreads();

  const float* xp = X   + (size_t)(row0 + lr)*CDIM + lq*8;
  float*       op = out + (size_t)(row0 + lr)*CDIM + lq*8;
  const bf16x8* wf8 = (const bf16x8*)Wf;

  f32x4  xa[3], xb[3];
  bf16x8 B[3][4];
  f32x4  acc[4] = {};

#define LDX(T) { xa[(T)%3] = *(const f32x4*)(xp + (T)*32); \
                 xb[(T)%3] = *(const f32x4*)(xp + (T)*32 + 4); }
#define LDBF(T) { B[(T)%3][0] = wf8[((T)*4+0)*64 + lane]; \
                  B[(T)%3][1] = wf8[((T)*4+1)*64 + lane]; \
                  B[(T)%3][2] = wf8[((T)*4+2)*64 + lane]; \
                  B[(T)%3][3] = wf8[((T)*4+3)*64 + lane]; }

  LDX(0) LDBF(0)
  LDX(1) LDBF(1)
  #pragma unroll
  for (int t = 0; t < 32; ++t){
    if (t + 2 < 32){ LDX(t+2) LDBF(t+2) }
    f32x4 g0 = *(const f32x4*)(gbS + t*32 + lq*8);
    f32x4 g1 = *(const f32x4*)(gbS + t*32 + lq*8 + 4);
    f32x4 va = xa[t%3], vb = xb[t%3];
    *(f32x4*)(op + t*32)     = va + g0;      // fused identity copy
    *(f32x4*)(op + t*32 + 4) = vb + g1;
    bf16x8 av;
    av[0]=(__bf16)va[0]; av[1]=(__bf16)va[1]; av[2]=(__bf16)va[2]; av[3]=(__bf16)va[3];
    av[4]=(__bf16)vb[0]; av[5]=(__bf16)vb[1]; av[6]=(__bf16)vb[2]; av[7]=(__bf16)vb[3];
    acc[0] = __builtin_amdgcn_mfma_f32_16x16x32_bf16(av, B[t%3][0], acc[0], 0,0,0);
    acc[1] = __builtin_amdgcn_mfma_f32_16x16x32_bf16(av, B[t%3][1], acc[1], 0,0,0);
    acc[2] = __builtin_amdgcn_mfma_f32_16x16x32_bf16(av, B[t%3][2], acc[2], 0,0,0);
    acc[3] = __builtin_amdgcn_mfma_f32_16x16x32_bf16(av, B[t%3][3], acc[3], 0,0,0);
  }
#undef LDX
#undef LDBF

  // Epilogue: +bd, exact gelu, write a, fused l2norm-dot scores
  const float* selb = seln + batch*64;
  float ss[4] = {0,0,0,0}, dt[4] = {0,0,0,0};
  float gv[4][4];
  #pragma unroll
  for (int j=0;j<4;j++){
    int col = 16*j + lr;
    float bdc = bd[col];
    float sc  = selb[col];
    #pragma unroll
    for (int r=0;r<4;r++){
      float y = acc[j][r] + bdc;
      float g = 0.5f * y * (1.0f + erff(y * 0.70710678118654752f));
      gv[j][r] = g;
      ss[r] += g*g;
      dt[r] += g*sc;
    }
  }
  #pragma unroll
  for (int r=0;r<4;r++){
    int row = row0 + 4*lq + r;
    #pragma unroll
    for (int j=0;j<4;j++)
      a_out[(size_t)row*DDIM + 16*j + lr] = gv[j][r];
  }
  #pragma unroll
  for (int m=1;m<16;m<<=1){
    #pragma unroll
    for (int r=0;r<4;r++){
      ss[r] += __shfl_xor(ss[r], m);
      dt[r] += __shfl_xor(dt[r], m);
    }
  }
  if (lr == 0){
    #pragma unroll
    for (int r=0;r<4;r++)
      scores[row0 + 4*lq + r] = dt[r] / fmaxf(sqrtf(ss[r]), 1e-12f);
  }
}

// ---------------- K2: per-batch exact top-64 via 8-bit radix select -----------------
__global__ __launch_bounds__(1024) void dsa_topk(const float* __restrict__ scores,
                                                 int* __restrict__ idxo){
  const int b = blockIdx.x, tid = threadIdx.x;
  const float* s = scores + b*NB;
  const int base = tid*16;
  unsigned key[16];
  #pragma unroll
  for (int i=0;i<16;i+=4){
    f32x4 f = *(const f32x4*)(s + base + i);
    #pragma unroll
    for (int c=0;c<4;c++){
      unsigned u = __float_as_uint(f[c]);
      key[i+c] = (u & 0x80000000u) ? ~u : (u | 0x80000000u);  // ascending uint order
    }
  }

  __shared__ unsigned bins[256];
  __shared__ unsigned sh_pref, sh_R;
  __shared__ int selIdx[64];
  __shared__ int eqIdx[256];
  __shared__ unsigned selCnt, eqCnt;

  unsigned prefix = 0, R = 64;
  for (int pass=0; pass<4; ++pass){
    const int shift = 24 - pass*8;
    if (tid < 256) bins[tid] = 0;
    __syncthreads();
    #pragma unroll
    for (int i=0;i<16;i++){
      unsigned k = key[i];
      bool ok;
      if (pass == 0) ok = true;
      else           ok = ((k >> (shift+8)) == prefix);
      if (ok) atomicAdd(&bins[(k >> shift) & 255u], 1u);
    }
    __syncthreads();
    if (tid < 64){
      unsigned c0 = bins[tid*4+0], c1 = bins[tid*4+1];
      unsigned c2 = bins[tid*4+2], c3 = bins[tid*4+3];
      unsigned gs = c0+c1+c2+c3;
      unsigned suf = gs;                       // inclusive suffix sum over 64 groups
      #pragma unroll
      for (int m=1;m<64;m<<=1){
        unsigned o = __shfl_down(suf, m);
        if (tid + m < 64) suf += o;
      }
      unsigned above = suf - gs;               // strictly-above-this-group count
      if (above < R && R <= suf){              // exactly one lane
        unsigned a3 = above;
        unsigned a2 = a3 + c3;
        unsigned a1 = a2 + c2;
        unsigned a0 = a1 + c1;
        unsigned bb, ab;
        if      (R <= a3 + c3){ bb = 3; ab = a3; }
        else if (R <= a2 + c2){ bb = 2; ab = a2; }
        else if (R <= a1 + c1){ bb = 1; ab = a1; }
        else                  { bb = 0; ab = a0; }
        sh_pref = (prefix << 8) | (tid*4 + bb);
        sh_R = R - ab;
      }
    }
    __syncthreads();
    prefix = sh_pref; R = sh_R;
    __syncthreads();
  }
  // prefix == exact key of 64th-largest; need R of the equal keys (smallest indices)
  if (tid == 0){ selCnt = 0; eqCnt = 0; }
  __syncthreads();
  #pragma unroll
  for (int i=0;i<16;i++){
    unsigned k = key[i];
    if (k > prefix){
      selIdx[atomicAdd(&selCnt, 1u)] = base + i;
    } else if (k == prefix){
      unsigned p = atomicAdd(&eqCnt, 1u);
      if (p < 256) eqIdx[p] = base + i;
    }
  }
  __syncthreads();
  if (tid == 0){
    unsigned n = eqCnt < 256u ? eqCnt : 256u;
    unsigned have = selCnt;
    for (unsigned r2 = 0; r2 < R; ++r2){
      int best = 0x7fffffff, bi = -1;
      for (unsigned e=0; e<n; e++)
        if (eqIdx[e] < best){ best = eqIdx[e]; bi = (int)e; }
      selIdx[have + r2] = best;
      eqIdx[bi] = 0x7fffffff;
    }
  }
  __syncthreads();
  if (tid < 64){                    // wave-0 bitonic sort ascending
    int x = selIdx[tid];
    #pragma unroll
    for (int size=2; size<=64; size<<=1){
      #pragma unroll
      for (int stride=size>>1; stride>0; stride>>=1){
        int ox = __shfl_xor(x, stride);
        bool up = ((tid & size) == 0);
        bool takeMin = (((tid & stride) == 0) == up);
        int mn = x < ox ? x : ox, mx = x < ox ? ox : x;
        x = takeMin ? mn : mx;
      }
    }
    idxo[b*64 + tid] = x;
  }
}

// ---------------- K3: fused per-batch tail: gather+LN+QKV+attention+Wo+enh ----------
__global__ __launch_bounds__(512) void dsa_tail(
    const float* __restrict__ a, const float* __restrict__ mq, const int* __restrict__ idx,
    const float* __restrict__ lnw, const float* __restrict__ lnb,
    const float* __restrict__ Wq, const float* __restrict__ bq,
    const float* __restrict__ Wk, const float* __restrict__ bk,
    const float* __restrict__ Wv, const float* __restrict__ bv,
    const float* __restrict__ Wo, const float* __restrict__ bo,
    float* __restrict__ enh)
{
  __shared__ float xln[80][64];
  __shared__ float qS[80][64];
  __shared__ float vS[80][68];     // padded: PV 4-group read -> 2-way (free)
  __shared__ float kT[64][81];     // K transposed, padded
  __shared__ float oS[80][64];
  __shared__ float WoS[64][64];
  __shared__ float rowbuf[8][84];  // per-wave prob row
  __shared__ int   sidx[64];

  const int b = blockIdx.x, tid = threadIdx.x;
  const int w = tid >> 6, lane = tid & 63;

  if (tid < 64) sidx[tid] = idx[b*64 + tid];
  for (int e = tid; e < 4096; e += 512) WoS[e>>6][e&63] = Wo[e];  // overlap with P0
  __syncthreads();

  // ---- P0: gather comb rows + layernorm (10 rows per wave, loads prefetched) ----
  {
    float lw = lnw[lane], lb = lnb[lane];
    float vals[10];
    #pragma unroll
    for (int i=0;i<10;i++){
      int s = w + 8*i;
      vals[i] = (s < 16) ? mq[s*64 + lane]
                         : a[((size_t)b*NB + sidx[s-16])*64 + lane];
    }
    #pragma unroll
    for (int i=0;i<10;i++){
      int s = w + 8*i;
      float val = vals[i];
      float sm = val, sq = val*val;
      #pragma unroll
      for (int m=1;m<64;m<<=1){ sm += __shfl_xor(sm,m); sq += __shfl_xor(sq,m); }
      float mu  = sm * (1.0f/64.0f);
      float var = sq * (1.0f/64.0f) - mu*mu;
      xln[s][lane] = (val - mu) * rsqrtf(var + 1e-5f) * lw + lb;
    }
  }
  __syncthreads();

  // ---- P1: QKV projections. W column in registers per lane. ----
  #pragma unroll 1
  for (int m = 0; m < 3; ++m){
    const float* Wm = (m==0) ? Wq : (m==1) ? Wk : Wv;
    const float* bm = (m==0) ? bq : (m==1) ? bk : bv;
    float wreg[64];
    #pragma unroll
    for (int c=0;c<64;c++) wreg[c] = Wm[c*64 + lane];
    float bias = bm[lane];
    #pragma unroll 1
    for (int s = w; s < 80; s += 8){
      float accv = bias;
      #pragma unroll
      for (int c4=0;c4<16;c4++){
        f32x4 x4 = *(const f32x4*)&xln[s][c4*4];
        accv += x4[0]*wreg[c4*4+0] + x4[1]*wreg[c4*4+1]
              + x4[2]*wreg[c4*4+2] + x4[3]*wreg[c4*4+3];
      }
      if (m==0)      qS[s][lane]  = accv;
      else if (m==1) kT[lane][s]  = accv;
      else           vS[s][lane]  = accv;
    }
  }
  __syncthreads();

  // ---- P2: fused scores+softmax+PV. Wave pair per head; rows 16..79 only. ----
  {
    const int h = w >> 1, h16 = h*16;
    const int i0 = 16 + (w & 1)*32;
    const int jj = lane >> 4, dd = lane & 15;
    #pragma unroll 2
    for (int ii = 0; ii < 32; ++ii){
      int i = i0 + ii;
      float v0 = 0.f, v1 = 0.f;
      #pragma unroll
      for (int d=0; d<16; ++d){
        float qd = qS[i][h16+d];
        v0 = fmaf(qd, kT[h16+d][lane],    v0);
        v1 = fmaf(qd, kT[h16+d][64 + dd], v1);
      }
      v0 *= 0.25f; v1 *= 0.25f;
      float mx = fmaxf(v0, v1);
      #pragma unroll
      for (int m2=1;m2<64;m2<<=1) mx = fmaxf(mx, __shfl_xor(mx,m2));
      float e0 = expf(v0 - mx);
      float e1 = expf(v1 - mx);
      float sm = e0 + ((lane < 16) ? e1 : 0.f);
      #pragma unroll
      for (int m2=1;m2<64;m2<<=1) sm += __shfl_xor(sm,m2);
      float inv = 1.0f / sm;
      rowbuf[w][lane] = e0 * inv;
      if (lane < 16) rowbuf[w][64+dd] = e1 * inv;
      // PV partials: lane = (jj,dd); same-wave LDS ordering guarantees visibility
      float part = 0.f;
      #pragma unroll
      for (int tt=0; tt<20; ++tt){
        int j = jj*20 + tt;
        part = fmaf(rowbuf[w][j], vS[j][h16+dd], part);
      }
      part += __shfl_xor(part, 16);
      part += __shfl_xor(part, 32);
      if (lane < 16) oS[i][h16+dd] = part;
    }
  }
  __syncthreads();

  // ---- P3: enh = comb_sparse + o @ Wo + bo ----
  for (int e = tid; e < 4096; e += 512){
    int s16 = e >> 6, cc = e & 63;
    float accv = bo[cc];
    #pragma unroll
    for (int d4=0; d4<16; ++d4){
      f32x4 o4 = *(const f32x4*)&oS[16+s16][d4*4];
      accv += o4[0]*WoS[d4*4+0][cc] + o4[1]*WoS[d4*4+1][cc]
            + o4[2]*WoS[d4*4+2][cc] + o4[3]*WoS[d4*4+3][cc];
    }
    float cmb = a[((size_t)b*NB + sidx[s16])*64 + cc];
    enh[(b*64 + s16)*64 + cc] = cmb + accv;
  }
}

// ---------------- K4: out[b, idx[j], :] += gamma * (enh[j] @ Wu) --------------------
__global__ __launch_bounds__(256) void dsa_scatter(
    const float* __restrict__ enh, const float* __restrict__ Wu,
    const float* __restrict__ gam, const int* __restrict__ idx,
    float* __restrict__ out)
{
  int blk = blockIdx.x;
  int b = blk >> 6, j = blk & 63;
  int tid = threadIdx.x;
  __shared__ float er[64];
  if (tid < 64) er[tid] = enh[(b*64+j)*64 + tid];
  __syncthreads();
  int n = idx[b*64 + j];
  float gamma = gam[0];
  int c0 = tid*4;
  float ax=0.f, ay=0.f, az=0.f, aw=0.f;
  #pragma unroll 8
  for (int d=0; d<64; ++d){
    float ev = er[d];
    f32x4 wr = *(const f32x4*)(Wu + d*CDIM + c0);
    ax += ev*wr[0]; ay += ev*wr[1]; az += ev*wr[2]; aw += ev*wr[3];
  }
  float* op = out + ((size_t)b*NB + n)*CDIM + c0;
  f32x4 cu = *(f32x4*)op;
  cu[0] += gamma*ax; cu[1] += gamma*ay; cu[2] += gamma*az; cu[3] += gamma*aw;
  *(f32x4*)op = cu;
}

extern "C" void kernel_launch(void* const* d_in, const int* in_sizes, int n_in,
                              void* d_out, int out_size, void* d_ws, size_t ws_size,
                              hipStream_t stream) {
  const float* X    = (const float*)d_in[0];
  const float* tf   = (const float*)d_in[1];
  const float* Wd   = (const float*)d_in[2];
  const float* bd   = (const float*)d_in[3];
  const float* Wu   = (const float*)d_in[4];
  const float* bu   = (const float*)d_in[5];
  const float* mq   = (const float*)d_in[6];
  const float* Wq   = (const float*)d_in[7];
  const float* bq   = (const float*)d_in[8];
  const float* Wk   = (const float*)d_in[9];
  const float* bk   = (const float*)d_in[10];
  const float* Wv   = (const float*)d_in[11];
  const float* bv   = (const float*)d_in[12];
  const float* Wo   = (const float*)d_in[13];
  const float* bo   = (const float*)d_in[14];
  const float* lnw  = (const float*)d_in[15];
  const float* lnb  = (const float*)d_in[16];
  const float* gam  = (const float*)d_in[17];
  float* out = (float*)d_out;

  float* ws_a               = (float*)d_ws;                 // 65536*64
  unsigned short* ws_wf     = (unsigned short*)(ws_a + (size_t)NROWS*DDIM);
  float* ws_scores          = (float*)(ws_wf + 64*CDIM);    // 65536
  float* ws_seln            = ws_scores + NROWS;            // 256
  float* ws_gbu             = ws_seln + 256;                // 1024
  int*   ws_idx             = (int*)(ws_gbu + 1024);        // 256
  float* ws_enh             = (float*)(ws_idx + 256);       // 4*64*64

  dsa_prep   <<<33,   256, 0, stream>>>(Wd, tf, bu, gam, ws_wf, ws_seln, ws_gbu);
  dsa_main   <<<1024, 256, 0, stream>>>(X, ws_wf, bd, ws_gbu, ws_seln,
                                        out, ws_a, ws_scores);
  dsa_topk   <<<4,   1024, 0, stream>>>(ws_scores, ws_idx);
  dsa_tail   <<<4,    512, 0, stream>>>(ws_a, mq, ws_idx, lnw, lnb,
                                        Wq, bq, Wk, bk, Wv, bv, Wo, bo, ws_enh);
  dsa_scatter<<<256,  256, 0, stream>>>(ws_enh, Wu, gam, ws_idx, out);
}

// Round 10
// 237.352 us; speedup vs baseline: 1.1525x; 1.0146x over previous
//
#include <hip/hip_runtime.h>
#include <hip/hip_bf16.h>
#include <math.h>

typedef __bf16 bf16x8 __attribute__((ext_vector_type(8)));
typedef __bf16 bf16x4 __attribute__((ext_vector_type(4)));
typedef unsigned short u16x8 __attribute__((ext_vector_type(8)));
typedef float f32x4 __attribute__((ext_vector_type(4)));

#define CDIM 1024
#define DDIM 64
#define NB   16384
#define NROWS 65536

// float -> bf16 bits, round-to-nearest-even (finite inputs)
__device__ __forceinline__ unsigned short f2bf(float x){
  unsigned int u = __float_as_uint(x);
  unsigned int lsb = (u >> 16) & 1u;
  u += 0x7fffu + lsb;
  return (unsigned short)(u >> 16);
}

// ---------------- K0: Wd -> fragment-major bf16 Wf; seln = l2norm(sel); gbu --------
// Wf element index: (t*4 + j)*64*8 + lane*8 + e  holds  Wd[k][n],
//   n = j*16 + (lane&15),  k = t*32 + (lane>>4)*8 + e      (t = 0..31, j = 0..3)
__global__ __launch_bounds__(256) void dsa_prep(
    const float* __restrict__ Wd, const float* __restrict__ tf,
    const float* __restrict__ bu, const float* __restrict__ gam,
    unsigned short* __restrict__ Wf, float* __restrict__ seln,
    float* __restrict__ gbu){
  int bb = blockIdx.x, tid = threadIdx.x;
  if (bb < 32){
    int g = bb*256 + tid;            // 0..8191
    int lane = g & 63, tj = g >> 6;  // tj = t*4+j
    int n  = ((tj & 3) << 4) + (lane & 15);
    int k0 = ((tj >> 2) << 5) + ((lane >> 4) << 3);
    u16x8 uv;
    #pragma unroll
    for (int e=0;e<8;e++) uv[e] = f2bf(Wd[(k0+e)*DDIM + n]);
    *(u16x8*)(Wf + (size_t)g*8) = uv;
  } else {
    int w = tid >> 6, lane = tid & 63;   // wave w = batch w
    float x = tf[w*(20*512) + lane];     // text_features[b,0,lane]
    float sq = x*x;
    #pragma unroll
    for (int m=1; m<64; m<<=1) sq += __shfl_xor(sq, m);
    seln[w*64 + lane] = x / fmaxf(sqrtf(sq), 1e-12f);
    float g = gam[0];
    f32x4 b4 = *(const f32x4*)(bu + tid*4);
    *(f32x4*)(gbu + tid*4) = g*b4;
  }
}

// ---------------- K1: fused  out=X+gbu | a=gelu(X@Wd+bd) | scores -------------------
// DRAM-facing pattern: per-instruction 128B-contiguous row segments. MFMA-facing
// pattern: wave-private LDS (bf16). Wave-local lgkmcnt(0)+sched_barrier fence at
// each phase start orders ds_write -> cross-lane ds_read WITHOUT draining vmcnt
// (X prefetch stays in flight). No block barriers.
__global__ __launch_bounds__(256, 4) void dsa_main(
    const float* __restrict__ X, const unsigned short* __restrict__ Wf,
    const float* __restrict__ bd, const float* __restrict__ gbu,
    const float* __restrict__ seln,
    float* __restrict__ out, float* __restrict__ a_out, float* __restrict__ scores)
{
  // 4 waves x 2 buffers x (16 rows x 136 u16) = 34,816 B
  __shared__ __align__(16) unsigned short Abuf[4][2][16*136];
  const int tid  = threadIdx.x;
  const int lane = tid & 63, w = tid >> 6;
  const int lr = lane & 15, lq = lane >> 4;
  const int row0 = blockIdx.x*64 + w*16;      // this wave's 16 rows
  const int batch = blockIdx.x >> 8;          // 256 blocks per batch
  const int r8 = lane >> 3, ck = lane & 7;    // staging: 8 rows x 8 chunk-slots

  const float* xbase = X   + (size_t)row0*CDIM;
  float*       obase = out + (size_t)row0*CDIM;
  const bf16x8* wf8 = (const bf16x8*)Wf;
  unsigned short* lds = &Abuf[w][0][0];

  f32x4  xr[2][4];    // [row-half][j]: rows r8, r8+8; chunks ck+8j
  f32x4  g[4];
  bf16x8 Bb[2][4];
  f32x4  acc[4] = {};

#define LBUF(P) (lds + (((P)&1)*(16*136)))

  // load phase-(P) tile: per instruction 8 rows x 128B contiguous segments
#define ISSUE_X(P) { \
  const float* xq = xbase + (P)*128; \
  xr[0][0]=*(const f32x4*)(xq + (size_t)(r8  )*CDIM + (ck+ 0)*4); \
  xr[0][1]=*(const f32x4*)(xq + (size_t)(r8  )*CDIM + (ck+ 8)*4); \
  xr[0][2]=*(const f32x4*)(xq + (size_t)(r8  )*CDIM + (ck+16)*4); \
  xr[0][3]=*(const f32x4*)(xq + (size_t)(r8  )*CDIM + (ck+24)*4); \
  xr[1][0]=*(const f32x4*)(xq + (size_t)(r8+8)*CDIM + (ck+ 0)*4); \
  xr[1][1]=*(const f32x4*)(xq + (size_t)(r8+8)*CDIM + (ck+ 8)*4); \
  xr[1][2]=*(const f32x4*)(xq + (size_t)(r8+8)*CDIM + (ck+16)*4); \
  xr[1][3]=*(const f32x4*)(xq + (size_t)(r8+8)*CDIM + (ck+24)*4); \
  g[0]=*(const f32x4*)(gbu + (P)*128 + (ck+ 0)*4); \
  g[1]=*(const f32x4*)(gbu + (P)*128 + (ck+ 8)*4); \
  g[2]=*(const f32x4*)(gbu + (P)*128 + (ck+16)*4); \
  g[3]=*(const f32x4*)(gbu + (P)*128 + (ck+24)*4); }

  // fused out-store (same contiguous shape) + bf16 cvt + LDS write
#define ST1(P, LP, H, J, RR) { \
  f32x4 o = xr[H][J] + g[J]; \
  *(f32x4*)(obase + (size_t)(RR)*CDIM + (P)*128 + (ck+8*(J))*4) = o; \
  bf16x4 bv; \
  bv[0]=(__bf16)xr[H][J][0]; bv[1]=(__bf16)xr[H][J][1]; \
  bv[2]=(__bf16)xr[H][J][2]; bv[3]=(__bf16)xr[H][J][3]; \
  *(bf16x4*)((LP) + (RR)*136 + (ck+8*(J))*4) = bv; }

#define STORE_STAGE(P, LP) { \
  ST1(P, LP, 0, 0, r8)   ST1(P, LP, 0, 1, r8)   ST1(P, LP, 0, 2, r8)   ST1(P, LP, 0, 3, r8) \
  ST1(P, LP, 1, 0, r8+8) ST1(P, LP, 1, 1, r8+8) ST1(P, LP, 1, 2, r8+8) ST1(P, LP, 1, 3, r8+8) }

#define LDB(T, I) { \
  Bb[I][0] = wf8[((T)*4+0)*64 + lane]; \
  Bb[I][1] = wf8[((T)*4+1)*64 + lane]; \
  Bb[I][2] = wf8[((T)*4+2)*64 + lane]; \
  Bb[I][3] = wf8[((T)*4+3)*64 + lane]; }

#define KSTEP(T, K0, P) { \
  if ((T)+1 < 32) LDB((T)+1, ((T)+1)&1) \
  bf16x8 av = *(const bf16x8*)(LBUF(P) + lr*136 + (K0)*32 + lq*8); \
  acc[0] = __builtin_amdgcn_mfma_f32_16x16x32_bf16(av, Bb[(T)&1][0], acc[0], 0,0,0); \
  acc[1] = __builtin_amdgcn_mfma_f32_16x16x32_bf16(av, Bb[(T)&1][1], acc[1], 0,0,0); \
  acc[2] = __builtin_amdgcn_mfma_f32_16x16x32_bf16(av, Bb[(T)&1][2], acc[2], 0,0,0); \
  acc[3] = __builtin_amdgcn_mfma_f32_16x16x32_bf16(av, Bb[(T)&1][3], acc[3], 0,0,0); }

  // FENCE: order previous phase's ds_writes before this phase's cross-lane
  // ds_reads, wave-locally (lgkm only; vmcnt untouched -> X prefetch lives).
#define PH(P) { \
  asm volatile("s_waitcnt lgkmcnt(0)" ::: "memory"); \
  __builtin_amdgcn_sched_barrier(0); \
  KSTEP(4*(P)+0, 0, P) KSTEP(4*(P)+1, 1, P) \
  KSTEP(4*(P)+2, 2, P) KSTEP(4*(P)+3, 3, P) \
  if ((P) < 7) STORE_STAGE((P)+1, LBUF((P)+1)) \
  if ((P) < 6) ISSUE_X((P)+2) }

  // prologue
  ISSUE_X(0)
  STORE_STAGE(0, LBUF(0))
  ISSUE_X(1)
  LDB(0, 0)

  PH(0) PH(1) PH(2) PH(3) PH(4) PH(5) PH(6) PH(7)

#undef LBUF
#undef ISSUE_X
#undef ST1
#undef STORE_STAGE
#undef LDB
#undef KSTEP
#undef PH

  // Epilogue: +bd, exact gelu, write a, fused l2norm-dot scores
  const float* selb = seln + batch*64;
  float ss[4] = {0,0,0,0}, dt[4] = {0,0,0,0};
  float gv[4][4];
  #pragma unroll
  for (int j=0;j<4;j++){
    int col = 16*j + lr;
    float bdc = bd[col];
    float sc  = selb[col];
    #pragma unroll
    for (int r=0;r<4;r++){
      float y = acc[j][r] + bdc;
      float gg = 0.5f * y * (1.0f + erff(y * 0.70710678118654752f));
      gv[j][r] = gg;
      ss[r] += gg*gg;
      dt[r] += gg*sc;
    }
  }
  #pragma unroll
  for (int r=0;r<4;r++){
    int row = row0 + 4*lq + r;
    #pragma unroll
    for (int j=0;j<4;j++)
      a_out[(size_t)row*DDIM + 16*j + lr] = gv[j][r];
  }
  #pragma unroll
  for (int m=1;m<16;m<<=1){
    #pragma unroll
    for (int r=0;r<4;r++){
      ss[r] += __shfl_xor(ss[r], m);
      dt[r] += __shfl_xor(dt[r], m);
    }
  }
  if (lr == 0){
    #pragma unroll
    for (int r=0;r<4;r++)
      scores[row0 + 4*lq + r] = dt[r] / fmaxf(sqrtf(ss[r]), 1e-12f);
  }
}

// ---------------- K2: per-batch exact top-64 via 8-bit radix select -----------------
__global__ __launch_bounds__(1024) void dsa_topk(const float* __restrict__ scores,
                                                 int* __restrict__ idxo){
  const int b = blockIdx.x, tid = threadIdx.x;
  const float* s = scores + b*NB;
  const int base = tid*16;
  unsigned key[16];
  #pragma unroll
  for (int i=0;i<16;i+=4){
    f32x4 f = *(const f32x4*)(s + base + i);
    #pragma unroll
    for (int c=0;c<4;c++){
      unsigned u = __float_as_uint(f[c]);
      key[i+c] = (u & 0x80000000u) ? ~u : (u | 0x80000000u);  // ascending uint order
    }
  }

  __shared__ unsigned bins[256];
  __shared__ unsigned sh_pref, sh_R;
  __shared__ int selIdx[64];
  __shared__ int eqIdx[256];
  __shared__ unsigned selCnt, eqCnt;

  unsigned prefix = 0, R = 64;
  for (int pass=0; pass<4; ++pass){
    const int shift = 24 - pass*8;
    if (tid < 256) bins[tid] = 0;
    __syncthreads();
    #pragma unroll
    for (int i=0;i<16;i++){
      unsigned k = key[i];
      bool ok;
      if (pass == 0) ok = true;
      else           ok = ((k >> (shift+8)) == prefix);
      if (ok) atomicAdd(&bins[(k >> shift) & 255u], 1u);
    }
    __syncthreads();
    if (tid < 64){
      unsigned c0 = bins[tid*4+0], c1 = bins[tid*4+1];
      unsigned c2 = bins[tid*4+2], c3 = bins[tid*4+3];
      unsigned gs = c0+c1+c2+c3;
      unsigned suf = gs;                       // inclusive suffix sum over 64 groups
      #pragma unroll
      for (int m=1;m<64;m<<=1){
        unsigned o = __shfl_down(suf, m);
        if (tid + m < 64) suf += o;
      }
      unsigned above = suf - gs;               // strictly-above-this-group count
      if (above < R && R <= suf){              // exactly one lane
        unsigned a3 = above;
        unsigned a2 = a3 + c3;
        unsigned a1 = a2 + c2;
        unsigned a0 = a1 + c1;
        unsigned bb, ab;
        if      (R <= a3 + c3){ bb = 3; ab = a3; }
        else if (R <= a2 + c2){ bb = 2; ab = a2; }
        else if (R <= a1 + c1){ bb = 1; ab = a1; }
        else                  { bb = 0; ab = a0; }
        sh_pref = (prefix << 8) | (tid*4 + bb);
        sh_R = R - ab;
      }
    }
    __syncthreads();
    prefix = sh_pref; R = sh_R;
    __syncthreads();
  }
  // prefix == exact key of 64th-largest; need R of the equal keys (smallest indices)
  if (tid == 0){ selCnt = 0; eqCnt = 0; }
  __syncthreads();
  #pragma unroll
  for (int i=0;i<16;i++){
    unsigned k = key[i];
    if (k > prefix){
      selIdx[atomicAdd(&selCnt, 1u)] = base + i;
    } else if (k == prefix){
      unsigned p = atomicAdd(&eqCnt, 1u);
      if (p < 256) eqIdx[p] = base + i;
    }
  }
  __syncthreads();
  if (tid == 0){
    unsigned n = eqCnt < 256u ? eqCnt : 256u;
    unsigned have = selCnt;
    for (unsigned r2 = 0; r2 < R; ++r2){
      int best = 0x7fffffff, bi = -1;
      for (unsigned e=0; e<n; e++)
        if (eqIdx[e] < best){ best = eqIdx[e]; bi = (int)e; }
      selIdx[have + r2] = best;
      eqIdx[bi] = 0x7fffffff;
    }
  }
  __syncthreads();
  if (tid < 64){                    // wave-0 bitonic sort ascending
    int x = selIdx[tid];
    #pragma unroll
    for (int size=2; size<=64; size<<=1){
      #pragma unroll
      for (int stride=size>>1; stride>0; stride>>=1){
        int ox = __shfl_xor(x, stride);
        bool up = ((tid & size) == 0);
        bool takeMin = (((tid & stride) == 0) == up);
        int mn = x < ox ? x : ox, mx = x < ox ? ox : x;
        x = takeMin ? mn : mx;
      }
    }
    idxo[b*64 + tid] = x;
  }
}

// ---------------- K3: fused per-batch tail: gather+LN+QKV+attention+Wo+enh ----------
__global__ __launch_bounds__(512) void dsa_tail(
    const float* __restrict__ a, const float* __restrict__ mq, const int* __restrict__ idx,
    const float* __restrict__ lnw, const float* __restrict__ lnb,
    const float* __restrict__ Wq, const float* __restrict__ bq,
    const float* __restrict__ Wk, const float* __restrict__ bk,
    const float* __restrict__ Wv, const float* __restrict__ bv,
    const float* __restrict__ Wo, const float* __restrict__ bo,
    float* __restrict__ enh)
{
  __shared__ float xln[80][64];
  __shared__ float qS[80][64];
  __shared__ float vS[80][68];     // padded: PV 4-group read -> 2-way (free)
  __shared__ float kT[64][81];     // K transposed, padded
  __shared__ float oS[80][64];
  __shared__ float WoS[64][64];
  __shared__ float rowbuf[8][84];  // per-wave prob row
  __shared__ int   sidx[64];

  const int b = blockIdx.x, tid = threadIdx.x;
  const int w = tid >> 6, lane = tid & 63;

  if (tid < 64) sidx[tid] = idx[b*64 + tid];
  for (int e = tid; e < 4096; e += 512) WoS[e>>6][e&63] = Wo[e];  // overlap with P0
  __syncthreads();

  // ---- P0: gather comb rows + layernorm (10 rows per wave, loads prefetched) ----
  {
    float lw = lnw[lane], lb = lnb[lane];
    float vals[10];
    #pragma unroll
    for (int i=0;i<10;i++){
      int s = w + 8*i;
      vals[i] = (s < 16) ? mq[s*64 + lane]
                         : a[((size_t)b*NB + sidx[s-16])*64 + lane];
    }
    #pragma unroll
    for (int i=0;i<10;i++){
      int s = w + 8*i;
      float val = vals[i];
      float sm = val, sq = val*val;
      #pragma unroll
      for (int m=1;m<64;m<<=1){ sm += __shfl_xor(sm,m); sq += __shfl_xor(sq,m); }
      float mu  = sm * (1.0f/64.0f);
      float var = sq * (1.0f/64.0f) - mu*mu;
      xln[s][lane] = (val - mu) * rsqrtf(var + 1e-5f) * lw + lb;
    }
  }
  __syncthreads();

  // ---- P1: QKV projections. W column in registers per lane. ----
  #pragma unroll 1
  for (int m = 0; m < 3; ++m){
    const float* Wm = (m==0) ? Wq : (m==1) ? Wk : Wv;
    const float* bm = (m==0) ? bq : (m==1) ? bk : bv;
    float wreg[64];
    #pragma unroll
    for (int c=0;c<64;c++) wreg[c] = Wm[c*64 + lane];
    float bias = bm[lane];
    #pragma unroll 1
    for (int s = w; s < 80; s += 8){
      float accv = bias;
      #pragma unroll
      for (int c4=0;c4<16;c4++){
        f32x4 x4 = *(const f32x4*)&xln[s][c4*4];
        accv += x4[0]*wreg[c4*4+0] + x4[1]*wreg[c4*4+1]
              + x4[2]*wreg[c4*4+2] + x4[3]*wreg[c4*4+3];
      }
      if (m==0)      qS[s][lane]  = accv;
      else if (m==1) kT[lane][s]  = accv;
      else           vS[s][lane]  = accv;
    }
  }
  __syncthreads();

  // ---- P2: fused scores+softmax+PV. Wave pair per head; rows 16..79 only. ----
  {
    const int h = w >> 1, h16 = h*16;
    const int i0 = 16 + (w & 1)*32;
    const int jj = lane >> 4, dd = lane & 15;
    #pragma unroll 2
    for (int ii = 0; ii < 32; ++ii){
      int i = i0 + ii;
      float v0 = 0.f, v1 = 0.f;
      #pragma unroll
      for (int d=0; d<16; ++d){
        float qd = qS[i][h16+d];
        v0 = fmaf(qd, kT[h16+d][lane],    v0);
        v1 = fmaf(qd, kT[h16+d][64 + dd], v1);
      }
      v0 *= 0.25f; v1 *= 0.25f;
      float mx = fmaxf(v0, v1);
      #pragma unroll
      for (int m2=1;m2<64;m2<<=1) mx = fmaxf(mx, __shfl_xor(mx,m2));
      float e0 = expf(v0 - mx);
      float e1 = expf(v1 - mx);
      float sm = e0 + ((lane < 16) ? e1 : 0.f);
      #pragma unroll
      for (int m2=1;m2<64;m2<<=1) sm += __shfl_xor(sm,m2);
      float inv = 1.0f / sm;
      rowbuf[w][lane] = e0 * inv;
      if (lane < 16) rowbuf[w][64+dd] = e1 * inv;
      asm volatile("s_waitcnt lgkmcnt(0)" ::: "memory");
      // PV partials: lane = (jj,dd)
      float part = 0.f;
      #pragma unroll
      for (int tt=0; tt<20; ++tt){
        int j = jj*20 + tt;
        part = fmaf(rowbuf[w][j], vS[j][h16+dd], part);
      }
      part += __shfl_xor(part, 16);
      part += __shfl_xor(part, 32);
      if (lane < 16) oS[i][h16+dd] = part;
    }
  }
  __syncthreads();

  // ---- P3: enh = comb_sparse + o @ Wo + bo ----
  for (int e = tid; e < 4096; e += 512){
    int s16 = e >> 6, cc = e & 63;
    float accv = bo[cc];
    #pragma unroll
    for (int d4=0; d4<16; ++d4){
      f32x4 o4 = *(const f32x4*)&oS[16+s16][d4*4];
      accv += o4[0]*WoS[d4*4+0][cc] + o4[1]*WoS[d4*4+1][cc]
            + o4[2]*WoS[d4*4+2][cc] + o4[3]*WoS[d4*4+3][cc];
    }
    float cmb = a[((size_t)b*NB + sidx[s16])*64 + cc];
    enh[(b*64 + s16)*64 + cc] = cmb + accv;
  }
}

// ---------------- K4: out[b, idx[j], :] += gamma * (enh[j] @ Wu) --------------------
__global__ __launch_bounds__(256) void dsa_scatter(
    const float* __restrict__ enh, const float* __restrict__ Wu,
    const float* __restrict__ gam, const int* __restrict__ idx,
    float* __restrict__ out)
{
  int blk = blockIdx.x;
  int b = blk >> 6, j = blk & 63;
  int tid = threadIdx.x;
  __shared__ float er[64];
  if (tid < 64) er[tid] = enh[(b*64+j)*64 + tid];
  __syncthreads();
  int n = idx[b*64 + j];
  float gamma = gam[0];
  int c0 = tid*4;
  float ax=0.f, ay=0.f, az=0.f, aw=0.f;
  #pragma unroll 8
  for (int d=0; d<64; ++d){
    float ev = er[d];
    f32x4 wr = *(const f32x4*)(Wu + d*CDIM + c0);
    ax += ev*wr[0]; ay += ev*wr[1]; az += ev*wr[2]; aw += ev*wr[3];
  }
  float* op = out + ((size_t)b*NB + n)*CDIM + c0;
  f32x4 cu = *(f32x4*)op;
  cu[0] += gamma*ax; cu[1] += gamma*ay; cu[2] += gamma*az; cu[3] += gamma*aw;
  *(f32x4*)op = cu;
}

extern "C" void kernel_launch(void* const* d_in, const int* in_sizes, int n_in,
                              void* d_out, int out_size, void* d_ws, size_t ws_size,
                              hipStream_t stream) {
  const float* X    = (const float*)d_in[0];
  const float* tf   = (const float*)d_in[1];
  const float* Wd   = (const float*)d_in[2];
  const float* bd   = (const float*)d_in[3];
  const float* Wu   = (const float*)d_in[4];
  const float* bu   = (const float*)d_in[5];
  const float* mq   = (const float*)d_in[6];
  const float* Wq   = (const float*)d_in[7];
  const float* bq   = (const float*)d_in[8];
  const float* Wk   = (const float*)d_in[9];
  const float* bk   = (const float*)d_in[10];
  const float* Wv   = (const float*)d_in[11];
  const float* bv   = (const float*)d_in[12];
  const float* Wo   = (const float*)d_in[13];
  const float* bo   = (const float*)d_in[14];
  const float* lnw  = (const float*)d_in[15];
  const float* lnb  = (const float*)d_in[16];
  const float* gam  = (const float*)d_in[17];
  float* out = (float*)d_out;

  float* ws_a               = (float*)d_ws;                 // 65536*64
  unsigned short* ws_wf     = (unsigned short*)(ws_a + (size_t)NROWS*DDIM);
  float* ws_scores          = (float*)(ws_wf + 64*CDIM);    // 65536
  float* ws_seln            = ws_scores + NROWS;            // 256
  float* ws_gbu             = ws_seln + 256;                // 1024
  int*   ws_idx             = (int*)(ws_gbu + 1024);        // 256
  float* ws_enh             = (float*)(ws_idx + 256);       // 4*64*64

  dsa_prep   <<<33,   256, 0, stream>>>(Wd, tf, bu, gam, ws_wf, ws_seln, ws_gbu);
  dsa_main   <<<1024, 256, 0, stream>>>(X, ws_wf, bd, ws_gbu, ws_seln,
                                        out, ws_a, ws_scores);
  dsa_topk   <<<4,   1024, 0, stream>>>(ws_scores, ws_idx);
  dsa_tail   <<<4,    512, 0, stream>>>(ws_a, mq, ws_idx, lnw, lnb,
                                        Wq, bq, Wk, bk, Wv, bv, Wo, bo, ws_enh);
  dsa_scatter<<<256,  256, 0, stream>>>(ws_enh, Wu, gam, ws_idx, out);
}

// Round 11
// 214.968 us; speedup vs baseline: 1.2725x; 1.1041x over previous
//
#include <hip/hip_runtime.h>
#include <hip/hip_bf16.h>
#include <math.h>

typedef __bf16 bf16x8 __attribute__((ext_vector_type(8)));
typedef __bf16 bf16x4 __attribute__((ext_vector_type(4)));
typedef unsigned short u16x8 __attribute__((ext_vector_type(8)));
typedef float f32x4 __attribute__((ext_vector_type(4)));

#define CDIM 1024
#define DDIM 64
#define NB   16384
#define NROWS 65536

// float -> bf16 bits, round-to-nearest-even (finite inputs)
__device__ __forceinline__ unsigned short f2bf(float x){
  unsigned int u = __float_as_uint(x);
  unsigned int lsb = (u >> 16) & 1u;
  u += 0x7fffu + lsb;
  return (unsigned short)(u >> 16);
}

// ---------------- K0: Wd -> fragment-major bf16 Wf; seln = l2norm(sel); gbu --------
// Wf element index: (t*4 + j)*64*8 + lane*8 + e  holds  Wd[k][n],
//   n = j*16 + (lane&15),  k = t*32 + (lane>>4)*8 + e      (t = 0..31, j = 0..3)
__global__ __launch_bounds__(256) void dsa_prep(
    const float* __restrict__ Wd, const float* __restrict__ tf,
    const float* __restrict__ bu, const float* __restrict__ gam,
    unsigned short* __restrict__ Wf, float* __restrict__ seln,
    float* __restrict__ gbu){
  int bb = blockIdx.x, tid = threadIdx.x;
  if (bb < 32){
    int g = bb*256 + tid;            // 0..8191
    int lane = g & 63, tj = g >> 6;  // tj = t*4+j
    int n  = ((tj & 3) << 4) + (lane & 15);
    int k0 = ((tj >> 2) << 5) + ((lane >> 4) << 3);
    u16x8 uv;
    #pragma unroll
    for (int e=0;e<8;e++) uv[e] = f2bf(Wd[(k0+e)*DDIM + n]);
    *(u16x8*)(Wf + (size_t)g*8) = uv;
  } else {
    int w = tid >> 6, lane = tid & 63;   // wave w = batch w
    float x = tf[w*(20*512) + lane];     // text_features[b,0,lane]
    float sq = x*x;
    #pragma unroll
    for (int m=1; m<64; m<<=1) sq += __shfl_xor(sq, m);
    seln[w*64 + lane] = x / fmaxf(sqrtf(sq), 1e-12f);
    float g = gam[0];
    f32x4 b4 = *(const f32x4*)(bu + tid*4);
    *(f32x4*)(gbu + tid*4) = g*b4;
  }
}

// ---------------- K1: fused  out=X+gbu | a=gelu(X@Wd+bd) | scores -------------------
// Every global load/store instruction = 64 lanes x 16B = 1KB CONTIGUOUS within one
// row (DRAM-friendly granule). Lane<->row transpose for MFMA goes through
// wave-private LDS (bf16, XOR-swizzled reads). Two wave-local lgkm fences per
// phase (RAW + WAR); no block barriers; X prefetched one phase ahead in regs.
__global__ __launch_bounds__(256) void dsa_main(
    const float* __restrict__ X, const unsigned short* __restrict__ Wf,
    const float* __restrict__ bd, const float* __restrict__ gbu,
    const float* __restrict__ seln,
    float* __restrict__ out, float* __restrict__ a_out, float* __restrict__ scores)
{
  // 4 waves x 16 rows x 256 bf16 (512 B pitch) = 32 KB
  __shared__ __align__(16) unsigned short Abuf[4][4096];
  const int tid  = threadIdx.x;
  const int lane = tid & 63, w = tid >> 6;
  const int lr = lane & 15, lq = lane >> 4;
  const int row0 = blockIdx.x*64 + w*16;      // this wave's 16 rows
  const int batch = blockIdx.x >> 8;          // 256 blocks per batch
  const int xmask = (lr & 7) << 3;            // XOR swizzle, u16 units

  const float* xb = X   + (size_t)row0*CDIM;
  float*       ob = out + (size_t)row0*CDIM;
  const bf16x8* wf8 = (const bf16x8*)Wf;
  unsigned short* lds = &Abuf[w][0];

  f32x4  xr[16];     // one phase of this wave's 16 rows (1KB-granule loads)
  f32x4  g;
  bf16x8 Bb[2][4];
  f32x4  acc[4] = {};

  auto issue_x = [&](int P){
    #pragma unroll
    for (int i=0;i<16;i++)
      xr[i] = *(const f32x4*)(xb + (size_t)i*CDIM + P*256 + lane*4);
    g = *(const f32x4*)(gbu + P*256 + lane*4);
  };
  auto out_cvt_write = [&](int P){
    #pragma unroll
    for (int i=0;i<16;i++){
      f32x4 o = xr[i] + g;
      *(f32x4*)(ob + (size_t)i*CDIM + P*256 + lane*4) = o;   // 1KB contiguous
      bf16x4 bv;
      bv[0]=(__bf16)xr[i][0]; bv[1]=(__bf16)xr[i][1];
      bv[2]=(__bf16)xr[i][2]; bv[3]=(__bf16)xr[i][3];
      *(bf16x4*)(lds + i*256 + ((lane*4) ^ ((i&7)<<3))) = bv; // linear, swizzled
    }
  };

  // prologue: phase 0 into regs, then LDS; first B frag
  issue_x(0);
  out_cvt_write(0);
  Bb[0][0] = wf8[0*64 + lane];
  Bb[0][1] = wf8[1*64 + lane];
  Bb[0][2] = wf8[2*64 + lane];
  Bb[0][3] = wf8[3*64 + lane];

  #pragma unroll
  for (int P = 0; P < 4; ++P){
    // RAW fence: this phase's ds_writes (prev iteration / prologue) visible
    asm volatile("s_waitcnt lgkmcnt(0)" ::: "memory");
    __builtin_amdgcn_sched_barrier(0);
    if (P < 3) issue_x(P+1);            // vmem only; overlaps compute below
    #pragma unroll
    for (int t = 0; t < 8; ++t){
      int kk = P*8 + t;
      if (t < 7 || P < 3){              // prefetch next B frag
        Bb[(t+1)&1][0] = wf8[((kk+1)*4+0)*64 + lane];
        Bb[(t+1)&1][1] = wf8[((kk+1)*4+1)*64 + lane];
        Bb[(t+1)&1][2] = wf8[((kk+1)*4+2)*64 + lane];
        Bb[(t+1)&1][3] = wf8[((kk+1)*4+3)*64 + lane];
      }
      int cidx = (t*32 + lq*8) ^ xmask;
      bf16x8 av = *(const bf16x8*)(lds + lr*256 + cidx);
      acc[0] = __builtin_amdgcn_mfma_f32_16x16x32_bf16(av, Bb[t&1][0], acc[0], 0,0,0);
      acc[1] = __builtin_amdgcn_mfma_f32_16x16x32_bf16(av, Bb[t&1][1], acc[1], 0,0,0);
      acc[2] = __builtin_amdgcn_mfma_f32_16x16x32_bf16(av, Bb[t&1][2], acc[2], 0,0,0);
      acc[3] = __builtin_amdgcn_mfma_f32_16x16x32_bf16(av, Bb[t&1][3], acc[3], 0,0,0);
    }
    // WAR fence: all ds_reads of phase P done before overwriting the buffer
    asm volatile("s_waitcnt lgkmcnt(0)" ::: "memory");
    __builtin_amdgcn_sched_barrier(0);
    if (P < 3) out_cvt_write(P+1);
  }

  // Epilogue: +bd, exact gelu, write a, fused l2norm-dot scores
  const float* selb = seln + batch*64;
  float ss[4] = {0,0,0,0}, dt[4] = {0,0,0,0};
  float gv[4][4];
  #pragma unroll
  for (int j=0;j<4;j++){
    int col = 16*j + lr;
    float bdc = bd[col];
    float sc  = selb[col];
    #pragma unroll
    for (int r=0;r<4;r++){
      float y = acc[j][r] + bdc;
      float gg = 0.5f * y * (1.0f + erff(y * 0.70710678118654752f));
      gv[j][r] = gg;
      ss[r] += gg*gg;
      dt[r] += gg*sc;
    }
  }
  #pragma unroll
  for (int r=0;r<4;r++){
    int row = row0 + 4*lq + r;
    #pragma unroll
    for (int j=0;j<4;j++)
      a_out[(size_t)row*DDIM + 16*j + lr] = gv[j][r];
  }
  #pragma unroll
  for (int m=1;m<16;m<<=1){
    #pragma unroll
    for (int r=0;r<4;r++){
      ss[r] += __shfl_xor(ss[r], m);
      dt[r] += __shfl_xor(dt[r], m);
    }
  }
  if (lr == 0){
    #pragma unroll
    for (int r=0;r<4;r++)
      scores[row0 + 4*lq + r] = dt[r] / fmaxf(sqrtf(ss[r]), 1e-12f);
  }
}

// ---------------- K2: per-batch exact top-64 via 8-bit radix select -----------------
__global__ __launch_bounds__(1024) void dsa_topk(const float* __restrict__ scores,
                                                 int* __restrict__ idxo){
  const int b = blockIdx.x, tid = threadIdx.x;
  const float* s = scores + b*NB;
  const int base = tid*16;
  unsigned key[16];
  #pragma unroll
  for (int i=0;i<16;i+=4){
    f32x4 f = *(const f32x4*)(s + base + i);
    #pragma unroll
    for (int c=0;c<4;c++){
      unsigned u = __float_as_uint(f[c]);
      key[i+c] = (u & 0x80000000u) ? ~u : (u | 0x80000000u);  // ascending uint order
    }
  }

  __shared__ unsigned bins[256];
  __shared__ unsigned sh_pref, sh_R;
  __shared__ int selIdx[64];
  __shared__ int eqIdx[256];
  __shared__ unsigned selCnt, eqCnt;

  unsigned prefix = 0, R = 64;
  for (int pass=0; pass<4; ++pass){
    const int shift = 24 - pass*8;
    if (tid < 256) bins[tid] = 0;
    __syncthreads();
    #pragma unroll
    for (int i=0;i<16;i++){
      unsigned k = key[i];
      bool ok;
      if (pass == 0) ok = true;
      else           ok = ((k >> (shift+8)) == prefix);
      if (ok) atomicAdd(&bins[(k >> shift) & 255u], 1u);
    }
    __syncthreads();
    if (tid < 64){
      unsigned c0 = bins[tid*4+0], c1 = bins[tid*4+1];
      unsigned c2 = bins[tid*4+2], c3 = bins[tid*4+3];
      unsigned gs = c0+c1+c2+c3;
      unsigned suf = gs;                       // inclusive suffix sum over 64 groups
      #pragma unroll
      for (int m=1;m<64;m<<=1){
        unsigned o = __shfl_down(suf, m);
        if (tid + m < 64) suf += o;
      }
      unsigned above = suf - gs;               // strictly-above-this-group count
      if (above < R && R <= suf){              // exactly one lane
        unsigned a3 = above;
        unsigned a2 = a3 + c3;
        unsigned a1 = a2 + c2;
        unsigned a0 = a1 + c1;
        unsigned bb, ab;
        if      (R <= a3 + c3){ bb = 3; ab = a3; }
        else if (R <= a2 + c2){ bb = 2; ab = a2; }
        else if (R <= a1 + c1){ bb = 1; ab = a1; }
        else                  { bb = 0; ab = a0; }
        sh_pref = (prefix << 8) | (tid*4 + bb);
        sh_R = R - ab;
      }
    }
    __syncthreads();
    prefix = sh_pref; R = sh_R;
    __syncthreads();
  }
  // prefix == exact key of 64th-largest; need R of the equal keys (smallest indices)
  if (tid == 0){ selCnt = 0; eqCnt = 0; }
  __syncthreads();
  #pragma unroll
  for (int i=0;i<16;i++){
    unsigned k = key[i];
    if (k > prefix){
      selIdx[atomicAdd(&selCnt, 1u)] = base + i;
    } else if (k == prefix){
      unsigned p = atomicAdd(&eqCnt, 1u);
      if (p < 256) eqIdx[p] = base + i;
    }
  }
  __syncthreads();
  if (tid == 0){
    unsigned n = eqCnt < 256u ? eqCnt : 256u;
    unsigned have = selCnt;
    for (unsigned r2 = 0; r2 < R; ++r2){
      int best = 0x7fffffff, bi = -1;
      for (unsigned e=0; e<n; e++)
        if (eqIdx[e] < best){ best = eqIdx[e]; bi = (int)e; }
      selIdx[have + r2] = best;
      eqIdx[bi] = 0x7fffffff;
    }
  }
  __syncthreads();
  if (tid < 64){                    // wave-0 bitonic sort ascending
    int x = selIdx[tid];
    #pragma unroll
    for (int size=2; size<=64; size<<=1){
      #pragma unroll
      for (int stride=size>>1; stride>0; stride>>=1){
        int ox = __shfl_xor(x, stride);
        bool up = ((tid & size) == 0);
        bool takeMin = (((tid & stride) == 0) == up);
        int mn = x < ox ? x : ox, mx = x < ox ? ox : x;
        x = takeMin ? mn : mx;
      }
    }
    idxo[b*64 + tid] = x;
  }
}

// ---------------- K3: fused per-batch tail: gather+LN+QKV+attention+Wo+enh ----------
__global__ __launch_bounds__(512) void dsa_tail(
    const float* __restrict__ a, const float* __restrict__ mq, const int* __restrict__ idx,
    const float* __restrict__ lnw, const float* __restrict__ lnb,
    const float* __restrict__ Wq, const float* __restrict__ bq,
    const float* __restrict__ Wk, const float* __restrict__ bk,
    const float* __restrict__ Wv, const float* __restrict__ bv,
    const float* __restrict__ Wo, const float* __restrict__ bo,
    float* __restrict__ enh)
{
  __shared__ float xln[80][64];
  __shared__ float qS[80][64];
  __shared__ float vS[80][68];     // padded: PV 4-group read -> 2-way (free)
  __shared__ float kT[64][81];     // K transposed, padded
  __shared__ float oS[80][64];
  __shared__ float WoS[64][64];
  __shared__ float rowbuf[8][84];  // per-wave prob row
  __shared__ int   sidx[64];

  const int b = blockIdx.x, tid = threadIdx.x;
  const int w = tid >> 6, lane = tid & 63;

  if (tid < 64) sidx[tid] = idx[b*64 + tid];
  for (int e = tid; e < 4096; e += 512) WoS[e>>6][e&63] = Wo[e];  // overlap with P0
  __syncthreads();

  // ---- P0: gather comb rows + layernorm (10 rows per wave, loads prefetched) ----
  {
    float lw = lnw[lane], lb = lnb[lane];
    float vals[10];
    #pragma unroll
    for (int i=0;i<10;i++){
      int s = w + 8*i;
      vals[i] = (s < 16) ? mq[s*64 + lane]
                         : a[((size_t)b*NB + sidx[s-16])*64 + lane];
    }
    #pragma unroll
    for (int i=0;i<10;i++){
      int s = w + 8*i;
      float val = vals[i];
      float sm = val, sq = val*val;
      #pragma unroll
      for (int m=1;m<64;m<<=1){ sm += __shfl_xor(sm,m); sq += __shfl_xor(sq,m); }
      float mu  = sm * (1.0f/64.0f);
      float var = sq * (1.0f/64.0f) - mu*mu;
      xln[s][lane] = (val - mu) * rsqrtf(var + 1e-5f) * lw + lb;
    }
  }
  __syncthreads();

  // ---- P1: QKV projections. W column in registers per lane. ----
  #pragma unroll 1
  for (int m = 0; m < 3; ++m){
    const float* Wm = (m==0) ? Wq : (m==1) ? Wk : Wv;
    const float* bm = (m==0) ? bq : (m==1) ? bk : bv;
    float wreg[64];
    #pragma unroll
    for (int c=0;c<64;c++) wreg[c] = Wm[c*64 + lane];
    float bias = bm[lane];
    #pragma unroll 1
    for (int s = w; s < 80; s += 8){
      float accv = bias;
      #pragma unroll
      for (int c4=0;c4<16;c4++){
        f32x4 x4 = *(const f32x4*)&xln[s][c4*4];
        accv += x4[0]*wreg[c4*4+0] + x4[1]*wreg[c4*4+1]
              + x4[2]*wreg[c4*4+2] + x4[3]*wreg[c4*4+3];
      }
      if (m==0)      qS[s][lane]  = accv;
      else if (m==1) kT[lane][s]  = accv;
      else           vS[s][lane]  = accv;
    }
  }
  __syncthreads();

  // ---- P2: fused scores+softmax+PV. Wave pair per head; rows 16..79 only. ----
  {
    const int h = w >> 1, h16 = h*16;
    const int i0 = 16 + (w & 1)*32;
    const int jj = lane >> 4, dd = lane & 15;
    #pragma unroll 2
    for (int ii = 0; ii < 32; ++ii){
      int i = i0 + ii;
      float v0 = 0.f, v1 = 0.f;
      #pragma unroll
      for (int d=0; d<16; ++d){
        float qd = qS[i][h16+d];
        v0 = fmaf(qd, kT[h16+d][lane],    v0);
        v1 = fmaf(qd, kT[h16+d][64 + dd], v1);
      }
      v0 *= 0.25f; v1 *= 0.25f;
      float mx = fmaxf(v0, v1);
      #pragma unroll
      for (int m2=1;m2<64;m2<<=1) mx = fmaxf(mx, __shfl_xor(mx,m2));
      float e0 = expf(v0 - mx);
      float e1 = expf(v1 - mx);
      float sm = e0 + ((lane < 16) ? e1 : 0.f);
      #pragma unroll
      for (int m2=1;m2<64;m2<<=1) sm += __shfl_xor(sm,m2);
      float inv = 1.0f / sm;
      rowbuf[w][lane] = e0 * inv;
      if (lane < 16) rowbuf[w][64+dd] = e1 * inv;
      asm volatile("s_waitcnt lgkmcnt(0)" ::: "memory");
      // PV partials: lane = (jj,dd)
      float part = 0.f;
      #pragma unroll
      for (int tt=0; tt<20; ++tt){
        int j = jj*20 + tt;
        part = fmaf(rowbuf[w][j], vS[j][h16+dd], part);
      }
      part += __shfl_xor(part, 16);
      part += __shfl_xor(part, 32);
      if (lane < 16) oS[i][h16+dd] = part;
    }
  }
  __syncthreads();

  // ---- P3: enh = comb_sparse + o @ Wo + bo ----
  for (int e = tid; e < 4096; e += 512){
    int s16 = e >> 6, cc = e & 63;
    float accv = bo[cc];
    #pragma unroll
    for (int d4=0; d4<16; ++d4){
      f32x4 o4 = *(const f32x4*)&oS[16+s16][d4*4];
      accv += o4[0]*WoS[d4*4+0][cc] + o4[1]*WoS[d4*4+1][cc]
            + o4[2]*WoS[d4*4+2][cc] + o4[3]*WoS[d4*4+3][cc];
    }
    float cmb = a[((size_t)b*NB + sidx[s16])*64 + cc];
    enh[(b*64 + s16)*64 + cc] = cmb + accv;
  }
}

// ---------------- K4: out[b, idx[j], :] += gamma * (enh[j] @ Wu) --------------------
__global__ __launch_bounds__(256) void dsa_scatter(
    const float* __restrict__ enh, const float* __restrict__ Wu,
    const float* __restrict__ gam, const int* __restrict__ idx,
    float* __restrict__ out)
{
  int blk = blockIdx.x;
  int b = blk >> 6, j = blk & 63;
  int tid = threadIdx.x;
  __shared__ float er[64];
  if (tid < 64) er[tid] = enh[(b*64+j)*64 + tid];
  __syncthreads();
  int n = idx[b*64 + j];
  float gamma = gam[0];
  int c0 = tid*4;
  float ax=0.f, ay=0.f, az=0.f, aw=0.f;
  #pragma unroll 8
  for (int d=0; d<64; ++d){
    float ev = er[d];
    f32x4 wr = *(const f32x4*)(Wu + d*CDIM + c0);
    ax += ev*wr[0]; ay += ev*wr[1]; az += ev*wr[2]; aw += ev*wr[3];
  }
  float* op = out + ((size_t)b*NB + n)*CDIM + c0;
  f32x4 cu = *(f32x4*)op;
  cu[0] += gamma*ax; cu[1] += gamma*ay; cu[2] += gamma*az; cu[3] += gamma*aw;
  *(f32x4*)op = cu;
}

extern "C" void kernel_launch(void* const* d_in, const int* in_sizes, int n_in,
                              void* d_out, int out_size, void* d_ws, size_t ws_size,
                              hipStream_t stream) {
  const float* X    = (const float*)d_in[0];
  const float* tf   = (const float*)d_in[1];
  const float* Wd   = (const float*)d_in[2];
  const float* bd   = (const float*)d_in[3];
  const float* Wu   = (const float*)d_in[4];
  const float* bu   = (const float*)d_in[5];
  const float* mq   = (const float*)d_in[6];
  const float* Wq   = (const float*)d_in[7];
  const float* bq   = (const float*)d_in[8];
  const float* Wk   = (const float*)d_in[9];
  const float* bk   = (const float*)d_in[10];
  const float* Wv   = (const float*)d_in[11];
  const float* bv   = (const float*)d_in[12];
  const float* Wo   = (const float*)d_in[13];
  const float* bo   = (const float*)d_in[14];
  const float* lnw  = (const float*)d_in[15];
  const float* lnb  = (const float*)d_in[16];
  const float* gam  = (const float*)d_in[17];
  float* out = (float*)d_out;

  float* ws_a               = (float*)d_ws;                 // 65536*64
  unsigned short* ws_wf     = (unsigned short*)(ws_a + (size_t)NROWS*DDIM);
  float* ws_scores          = (float*)(ws_wf + 64*CDIM);    // 65536
  float* ws_seln            = ws_scores + NROWS;            // 256
  float* ws_gbu             = ws_seln + 256;                // 1024
  int*   ws_idx             = (int*)(ws_gbu + 1024);        // 256
  float* ws_enh             = (float*)(ws_idx + 256);       // 4*64*64

  dsa_prep   <<<33,   256, 0, stream>>>(Wd, tf, bu, gam, ws_wf, ws_seln, ws_gbu);
  dsa_main   <<<1024, 256, 0, stream>>>(X, ws_wf, bd, ws_gbu, ws_seln,
                                        out, ws_a, ws_scores);
  dsa_topk   <<<4,   1024, 0, stream>>>(ws_scores, ws_idx);
  dsa_tail   <<<4,    512, 0, stream>>>(ws_a, mq, ws_idx, lnw, lnb,
                                        Wq, bq, Wk, bk, Wv, bv, Wo, bo, ws_enh);
  dsa_scatter<<<256,  256, 0, stream>>>(ws_enh, Wu, gam, ws_idx, out);
}